// Round 2
// baseline (13431.752 us; speedup 1.0000x reference)
//
#include <hip/hip_runtime.h>

#define H    51
#define G    153        // 3*H
#define BB   2048       // batch
#define TSEQ 1024       // input timesteps
#define NB   8          // batch rows per workgroup
#define WPAD 52         // padded weight-row length (f32); 208B rows keep 16B align for b128

__device__ __forceinline__ float sigm(float x) {
    return 1.0f / (1.0f + __expf(-x));
}
__device__ __forceinline__ float tanh_(float x) {
    return 1.0f - 2.0f / (__expf(2.0f * x) + 1.0f);
}

// dot of a 51-long f32 LDS row with a 51-long f32 register array
__device__ __forceinline__ float dot51f(const float* __restrict__ wr, const float* __restrict__ h) {
    float a0 = 0.f, a1 = 0.f, a2 = 0.f, a3 = 0.f;
#pragma unroll
    for (int j = 0; j < 48; j += 4) {
        a0 = fmaf(wr[j],     h[j],     a0);
        a1 = fmaf(wr[j + 1], h[j + 1], a1);
        a2 = fmaf(wr[j + 2], h[j + 2], a2);
        a3 = fmaf(wr[j + 3], h[j + 3], a3);
    }
    a0 = fmaf(wr[48], h[48], a0);
    a1 = fmaf(wr[49], h[49], a1);
    a2 = fmaf(wr[50], h[50], a2);
    return (a0 + a1) + (a2 + a3);
}

struct SM {
    float Wcat[306 * WPAD];        // rows 0..152: W_hh1 ; rows 153..305: W_hh2
    float Wi2[G * WPAD];           // W_ih2
    float X[NB][2 * G];            // [0..152]: gh1 then gi2 ; [153..305]: gh2
    float h1[NB][WPAD];
    float h2[NB][WPAD];
    float bhh[2 * G];              // b_hh1 ++ b_hh2
    float wih1[G];
    float bih1[G];
    float bih2[G];
    float wlin[H];
    float olds[NB];
    float blin;
};

__global__ __launch_bounds__(256, 1) void gru_persist(
    const float* __restrict__ inp, const int* __restrict__ fut,
    const float* __restrict__ wih1, const float* __restrict__ whh1,
    const float* __restrict__ bih1, const float* __restrict__ bhh1,
    const float* __restrict__ wih2, const float* __restrict__ whh2,
    const float* __restrict__ bih2, const float* __restrict__ bhh2,
    const float* __restrict__ wlin, const float* __restrict__ blin,
    float* __restrict__ out)
{
    extern __shared__ char smem_raw[];
    SM& sm = *reinterpret_cast<SM*>(smem_raw);

    const int tid = threadIdx.x;
    const int bg  = blockIdx.x;
    const int b   = tid >> 5;   // 0..7  batch-local
    const int s   = tid & 31;   // 0..31 slot

    // ---- one-time init: stage weights into LDS ----
    for (int idx = tid; idx < 306 * 51; idx += 256) {
        int r = idx / 51, k = idx - r * 51;
        sm.Wcat[r * WPAD + k] = (r < G) ? whh1[idx] : whh2[idx - G * 51];
    }
    for (int idx = tid; idx < G * 51; idx += 256) {
        int r = idx / 51, k = idx - r * 51;
        sm.Wi2[r * WPAD + k] = wih2[idx];
    }
    for (int i = tid; i < 2 * G; i += 256) sm.bhh[i] = (i < G) ? bhh1[i] : bhh2[i - G];
    for (int i = tid; i < G; i += 256) {
        sm.wih1[i] = wih1[i];
        sm.bih1[i] = bih1[i];
        sm.bih2[i] = bih2[i];
    }
    for (int i = tid; i < H; i += 256) sm.wlin[i] = wlin[i];
    for (int i = tid; i < NB * WPAD; i += 256) { ((float*)sm.h1)[i] = 0.f; ((float*)sm.h2)[i] = 0.f; }
    if (tid < NB) sm.olds[tid] = 0.f;
    if (tid == 0) sm.blin = blin[0];
    __syncthreads();

    const float blin_r = sm.blin;
    const int   TT     = TSEQ + fut[0];
    float* Xb = sm.X[b];

    // input prefetch: 4 timesteps (16B) per chunk
    const float* xrow = inp + (size_t)(bg * NB + b) * TSEQ;
    float4 xcur = make_float4(0.f, 0.f, 0.f, 0.f);
    float4 xnxt = *(const float4*)(xrow);   // chunk for t=0..3

    for (int t = 0; t < TT; ++t) {
        // ---- step input ----
        float xv;
        if (t < TSEQ) {
            if ((t & 3) == 0) {
                xcur = xnxt;
                if (t + 4 < TSEQ) xnxt = *(const float4*)(xrow + t + 4);
            }
            int q = t & 3;
            xv = (q == 0) ? xcur.x : (q == 1) ? xcur.y : (q == 2) ? xcur.z : xcur.w;
        } else {
            xv = sm.olds[b];          // autoregressive feedback (f32, unrounded)
        }

        // ---- phase 1: gh1 = W_hh1 h1 + b_hh1 ; gh2 = W_hh2 h2 + b_hh2 ----
        float h1r[H], h2r[H];
#pragma unroll
        for (int k = 0; k < H; ++k) { h1r[k] = sm.h1[b][k]; h2r[k] = sm.h2[b][k]; }
#pragma unroll
        for (int i = 0; i < 10; ++i) {
            int r = s + 32 * i;
            if (r < 306) {
                const float* wr = &sm.Wcat[r * WPAD];
                float acc;
                if (i < 4)      acc = dot51f(wr, h1r);
                else if (i > 4) acc = dot51f(wr, h2r);
                else            acc = (r < G) ? dot51f(wr, h1r) : dot51f(wr, h2r);
                Xb[r] = acc + sm.bhh[r];
            }
        }
        __syncthreads();

        // ---- phase 3: GRU1 elementwise -> h1' ----
#pragma unroll
        for (int u = 0; u < 2; ++u) {
            int j = s + 32 * u;
            if (j < H) {
                float ir  = fmaf(xv, sm.wih1[j],         sm.bih1[j]);
                float iz  = fmaf(xv, sm.wih1[j + H],     sm.bih1[j + H]);
                float in_ = fmaf(xv, sm.wih1[j + 2 * H], sm.bih1[j + 2 * H]);
                float rg = sigm(ir + Xb[j]);
                float zg = sigm(iz + Xb[j + H]);
                float ng = tanh_(fmaf(rg, Xb[j + 2 * H], in_));
                float ho = sm.h1[b][j];
                sm.h1[b][j] = (1.0f - zg) * ng + zg * ho;
            }
        }
        __syncthreads();

        // ---- phase 5: gi2 = W_ih2 h1' + b_ih2 (overwrites gh1 region) ----
#pragma unroll
        for (int k = 0; k < H; ++k) h1r[k] = sm.h1[b][k];
#pragma unroll
        for (int i = 0; i < 5; ++i) {
            int r = s + 32 * i;
            if (r < G) {
                float acc = dot51f(&sm.Wi2[r * WPAD], h1r);
                Xb[r] = acc + sm.bih2[r];
            }
        }
        __syncthreads();

        // ---- phase 7: GRU2 elementwise -> h2', out = w_lin . h2' + b_lin ----
        float p = 0.f;
#pragma unroll
        for (int u = 0; u < 2; ++u) {
            int j = s + 32 * u;
            if (j < H) {
                float rg = sigm(Xb[j] + Xb[G + j]);
                float zg = sigm(Xb[j + H] + Xb[G + j + H]);
                float ng = tanh_(fmaf(rg, Xb[G + j + 2 * H], Xb[j + 2 * H]));
                float ho = sm.h2[b][j];
                float hn = (1.0f - zg) * ng + zg * ho;
                sm.h2[b][j] = hn;
                p = fmaf(sm.wlin[j], hn, p);
            }
        }
        p += __shfl_xor(p, 1);
        p += __shfl_xor(p, 2);
        p += __shfl_xor(p, 4);
        p += __shfl_xor(p, 8);
        p += __shfl_xor(p, 16);
        if (s == 0) {
            float o = p + blin_r;
            sm.olds[b] = o;
            out[(size_t)(bg * NB + b) * TT + t] = o;
        }
        __syncthreads();
    }
}

extern "C" void kernel_launch(void* const* d_in, const int* in_sizes, int n_in,
                              void* d_out, int out_size, void* d_ws, size_t ws_size,
                              hipStream_t stream) {
    (void)in_sizes; (void)n_in; (void)d_ws; (void)ws_size; (void)out_size;
    hipFuncSetAttribute(reinterpret_cast<const void*>(gru_persist),
                        hipFuncAttributeMaxDynamicSharedMemorySize, (int)sizeof(SM));
    gru_persist<<<BB / NB, 256, sizeof(SM), stream>>>(
        (const float*)d_in[0], (const int*)d_in[1],
        (const float*)d_in[2], (const float*)d_in[3], (const float*)d_in[4], (const float*)d_in[5],
        (const float*)d_in[6], (const float*)d_in[7], (const float*)d_in[8], (const float*)d_in[9],
        (const float*)d_in[10], (const float*)d_in[11],
        (float*)d_out);
}

// Round 3
// 3044.290 us; speedup vs baseline: 4.4121x; 4.4121x over previous
//
#include <hip/hip_runtime.h>

#define H    51
#define G    153        // 3*H
#define BB   2048       // batch
#define TSEQ 1024       // input timesteps
#define NB   8          // batch rows per workgroup
#define NT   640        // threads per WG (10 waves)
#define HP   52         // padded h-row (f32), 208B = 13 x 16B
#define XS   308        // padded gate-row stride

__device__ __forceinline__ float sigm(float x) { return 1.0f / (1.0f + __expf(-x)); }
__device__ __forceinline__ float tanh_(float x) { return 1.0f - 2.0f / (__expf(2.0f * x) + 1.0f); }

struct SM {
    float h[2][NB][HP];            // h1, h2 (padded, [51] stays 0)
    float X[NB][XS];               // [0..152]: gh1 then gi2 ; [153..305]: gh2
    alignas(16) float xstep[NB][4];
    float bhh[2 * G];              // b_hh1 ++ b_hh2
    float wih1[G];
    float bih1[G];
    float bih2[G];
    float wlin[H];
    float olds[NB];
    float blin;
};

__global__ __launch_bounds__(NT, 1) void gru_persist(
    const float* __restrict__ inp, const int* __restrict__ fut,
    const float* __restrict__ wih1, const float* __restrict__ whh1,
    const float* __restrict__ bih1, const float* __restrict__ bhh1,
    const float* __restrict__ wih2, const float* __restrict__ whh2,
    const float* __restrict__ bih2, const float* __restrict__ bhh2,
    const float* __restrict__ wlin, const float* __restrict__ blin,
    float* __restrict__ out)
{
    __shared__ SM sm;
    const int t  = threadIdx.x;
    const int bg = blockIdx.x;

    // ---- static per-thread task mapping ----
    // P1: t<612 : row r1 = t>>1 of [W_hh1 ; W_hh2], batches bh1..bh1+3
    const int  r1   = t >> 1;
    const int  bh1  = (t & 1) * 4;
    const bool doP1 = (t < 612);
    const int  lay1 = (r1 < G) ? 0 : 1;
    // P5: t<306 : row r5 = t>>1 of W_ih2, batches bh5..bh5+3
    const int  r5   = r1;
    const int  bh5  = bh1;
    const bool doP5 = (t < 306);
    // P3/P7 elementwise: t<408 : (be, je)
    const bool doE  = (t < 408);
    const int  be   = t / 51;
    const int  je   = t - be * 51;
    // P8 reduce: t<256 : (br, sr)
    const int  br   = t >> 5;
    const int  sr   = t & 31;
    // x staging: t in [632,640)
    const bool doX  = (t >= 632);
    const int  bs   = t - 632;

    // ---- register-resident weights ----
    float w1[HP];   // Wcat row r1
    float w5[HP];   // W_ih2 row r5
#pragma unroll
    for (int k = 0; k < HP; ++k) { w1[k] = 0.f; w5[k] = 0.f; }
    if (doP1) {
        const float* src = (r1 < G) ? (whh1 + r1 * H) : (whh2 + (r1 - G) * H);
#pragma unroll
        for (int k = 0; k < H; ++k) w1[k] = src[k];
    }
    if (doP5) {
        const float* src = wih2 + r5 * H;
#pragma unroll
        for (int k = 0; k < H; ++k) w5[k] = src[k];
    }

    // ---- one-time LDS init ----
    for (int i = t; i < 2 * NB * HP; i += NT) ((float*)sm.h)[i] = 0.f;
    if (t < 2 * G) sm.bhh[t] = (t < G) ? bhh1[t] : bhh2[t - G];
    if (t < G) { sm.wih1[t] = wih1[t]; sm.bih1[t] = bih1[t]; sm.bih2[t] = bih2[t]; }
    if (t < H) sm.wlin[t] = wlin[t];
    if (t < NB) sm.olds[t] = 0.f;
    if (t == 0) sm.blin = blin[0];

    const float* xrow = inp + (size_t)(bg * NB + bs) * TSEQ;  // valid only for doX
    float4 xnxt = make_float4(0.f, 0.f, 0.f, 0.f);
    if (doX) xnxt = *(const float4*)(xrow);                   // x[0..3]
    __syncthreads();

    const int TT = TSEQ + fut[0];

    for (int ts = 0; ts < TT; ++ts) {
        // ---- P1: gh1 = W_hh1 h1 + b_hh1 ; gh2 = W_hh2 h2 + b_hh2 (+x staging) ----
        if (doP1) {
            const float4* h4a = (const float4*)&sm.h[lay1][bh1 + 0][0];
            const float4* h4b = (const float4*)&sm.h[lay1][bh1 + 1][0];
            const float4* h4c = (const float4*)&sm.h[lay1][bh1 + 2][0];
            const float4* h4d = (const float4*)&sm.h[lay1][bh1 + 3][0];
            float a0 = 0.f, a1 = 0.f, a2 = 0.f, a3 = 0.f;
#pragma unroll
            for (int k4 = 0; k4 < 13; ++k4) {
                float4 va = h4a[k4], vb = h4b[k4], vc = h4c[k4], vd = h4d[k4];
                a0 = fmaf(w1[4*k4], va.x, a0); a0 = fmaf(w1[4*k4+1], va.y, a0);
                a0 = fmaf(w1[4*k4+2], va.z, a0); a0 = fmaf(w1[4*k4+3], va.w, a0);
                a1 = fmaf(w1[4*k4], vb.x, a1); a1 = fmaf(w1[4*k4+1], vb.y, a1);
                a1 = fmaf(w1[4*k4+2], vb.z, a1); a1 = fmaf(w1[4*k4+3], vb.w, a1);
                a2 = fmaf(w1[4*k4], vc.x, a2); a2 = fmaf(w1[4*k4+1], vc.y, a2);
                a2 = fmaf(w1[4*k4+2], vc.z, a2); a2 = fmaf(w1[4*k4+3], vc.w, a2);
                a3 = fmaf(w1[4*k4], vd.x, a3); a3 = fmaf(w1[4*k4+1], vd.y, a3);
                a3 = fmaf(w1[4*k4+2], vd.z, a3); a3 = fmaf(w1[4*k4+3], vd.w, a3);
            }
            float bias = sm.bhh[r1];
            sm.X[bh1 + 0][r1] = a0 + bias;
            sm.X[bh1 + 1][r1] = a1 + bias;
            sm.X[bh1 + 2][r1] = a2 + bias;
            sm.X[bh1 + 3][r1] = a3 + bias;
        }
        if (doX && ts < TSEQ && (ts & 3) == 0) {
            *(float4*)&sm.xstep[bs][0] = xnxt;
            if (ts + 4 < TSEQ) xnxt = *(const float4*)(xrow + ts + 4);
        }
        __syncthreads();

        // ---- P3: GRU1 elementwise -> h1' ----
        if (doE) {
            float xv = (ts < TSEQ) ? sm.xstep[be][ts & 3] : sm.olds[be];
            float rg = sigm(fmaf(xv, sm.wih1[je],       sm.bih1[je])       + sm.X[be][je]);
            float zg = sigm(fmaf(xv, sm.wih1[je + H],   sm.bih1[je + H])   + sm.X[be][je + H]);
            float in_ = fmaf(xv, sm.wih1[je + 2 * H], sm.bih1[je + 2 * H]);
            float ng = tanh_(fmaf(rg, sm.X[be][je + 2 * H], in_));
            float ho = sm.h[0][be][je];
            sm.h[0][be][je] = (1.0f - zg) * ng + zg * ho;
        }
        __syncthreads();

        // ---- P5: gi2 = W_ih2 h1' + b_ih2 (overwrites gh1 region of X) ----
        if (doP5) {
            const float4* h4a = (const float4*)&sm.h[0][bh5 + 0][0];
            const float4* h4b = (const float4*)&sm.h[0][bh5 + 1][0];
            const float4* h4c = (const float4*)&sm.h[0][bh5 + 2][0];
            const float4* h4d = (const float4*)&sm.h[0][bh5 + 3][0];
            float a0 = 0.f, a1 = 0.f, a2 = 0.f, a3 = 0.f;
#pragma unroll
            for (int k4 = 0; k4 < 13; ++k4) {
                float4 va = h4a[k4], vb = h4b[k4], vc = h4c[k4], vd = h4d[k4];
                a0 = fmaf(w5[4*k4], va.x, a0); a0 = fmaf(w5[4*k4+1], va.y, a0);
                a0 = fmaf(w5[4*k4+2], va.z, a0); a0 = fmaf(w5[4*k4+3], va.w, a0);
                a1 = fmaf(w5[4*k4], vb.x, a1); a1 = fmaf(w5[4*k4+1], vb.y, a1);
                a1 = fmaf(w5[4*k4+2], vb.z, a1); a1 = fmaf(w5[4*k4+3], vb.w, a1);
                a2 = fmaf(w5[4*k4], vc.x, a2); a2 = fmaf(w5[4*k4+1], vc.y, a2);
                a2 = fmaf(w5[4*k4+2], vc.z, a2); a2 = fmaf(w5[4*k4+3], vc.w, a2);
                a3 = fmaf(w5[4*k4], vd.x, a3); a3 = fmaf(w5[4*k4+1], vd.y, a3);
                a3 = fmaf(w5[4*k4+2], vd.z, a3); a3 = fmaf(w5[4*k4+3], vd.w, a3);
            }
            float bias = sm.bih2[r5];
            sm.X[bh5 + 0][r5] = a0 + bias;
            sm.X[bh5 + 1][r5] = a1 + bias;
            sm.X[bh5 + 2][r5] = a2 + bias;
            sm.X[bh5 + 3][r5] = a3 + bias;
        }
        __syncthreads();

        // ---- P7: GRU2 elementwise -> h2' ----
        if (doE) {
            float rg = sigm(sm.X[be][je]         + sm.X[be][G + je]);
            float zg = sigm(sm.X[be][je + H]     + sm.X[be][G + je + H]);
            float ng = tanh_(fmaf(rg, sm.X[be][G + je + 2 * H], sm.X[be][je + 2 * H]));
            float ho = sm.h[1][be][je];
            sm.h[1][be][je] = (1.0f - zg) * ng + zg * ho;
        }
        __syncthreads();

        // ---- P8: out = w_lin . h2' + b_lin (overlaps next P1; disjoint LDS) ----
        if (t < 256) {
            float p = sm.wlin[sr] * sm.h[1][br][sr];
            if (sr < H - 32) p = fmaf(sm.wlin[sr + 32], sm.h[1][br][sr + 32], p);
            p += __shfl_xor(p, 1);
            p += __shfl_xor(p, 2);
            p += __shfl_xor(p, 4);
            p += __shfl_xor(p, 8);
            p += __shfl_xor(p, 16);
            if (sr == 0) {
                float o = p + sm.blin;
                sm.olds[br] = o;                       // read by P3 only after next barrier
                out[(size_t)(bg * NB + br) * TT + ts] = o;
            }
        }
    }
}

extern "C" void kernel_launch(void* const* d_in, const int* in_sizes, int n_in,
                              void* d_out, int out_size, void* d_ws, size_t ws_size,
                              hipStream_t stream) {
    (void)in_sizes; (void)n_in; (void)d_ws; (void)ws_size; (void)out_size;
    gru_persist<<<BB / NB, NT, 0, stream>>>(
        (const float*)d_in[0], (const int*)d_in[1],
        (const float*)d_in[2], (const float*)d_in[3], (const float*)d_in[4], (const float*)d_in[5],
        (const float*)d_in[6], (const float*)d_in[7], (const float*)d_in[8], (const float*)d_in[9],
        (const float*)d_in[10], (const float*)d_in[11],
        (float*)d_out);
}